// Round 6
// baseline (1796.592 us; speedup 1.0000x reference)
//
#include <hip/hip_runtime.h>
#include <hip/hip_bf16.h>
#include <stdint.h>

// Problem constants (from reference setup_inputs)
#define N_ROWS 8192
#define DIM    768
#define LAT    24576
#define KSEL   32

using bf16x8 = __attribute__((ext_vector_type(8))) short;   // 8 bf16 in 4 VGPRs
using f32x4  = __attribute__((ext_vector_type(4))) float;   // MFMA accumulator

__device__ __forceinline__ unsigned short f2bf(float f) {   // RNE f32->bf16
  unsigned int b = __float_as_uint(f);
  return (unsigned short)((b + 0x7FFFu + ((b >> 16) & 1u)) >> 16);
}
__device__ __forceinline__ float bf2f(unsigned short u) {
  return __uint_as_float(((unsigned int)u) << 16);
}
__device__ __forceinline__ unsigned int mapf(float f) {     // ascending total order
  unsigned int u = __float_as_uint(f);
  return (u & 0x80000000u) ? ~u : (u | 0x80000000u);
}

// ---------------------------------------------------------------------------
// Kernel 1: xn = (x - pre_bias) / max(||x - pre_bias||, 1e-12); bf16 copy.
// fp64 norm accumulation (order-robust); per-element fp32 DIVISION like np
// (r5 lesson: align the per-element rounding channel with the reference).
// ---------------------------------------------------------------------------
__global__ __launch_bounds__(192) void k_norm(const float* __restrict__ x,
                                              const float* __restrict__ pre_bias,
                                              float* __restrict__ xn,
                                              unsigned short* __restrict__ xnbf) {
  const int row = blockIdx.x;
  const int t   = threadIdx.x;
  float4 xc = *(const float4*)&x[(size_t)row * DIM + t * 4];
  float4 pb = *(const float4*)&pre_bias[t * 4];
  xc.x -= pb.x; xc.y -= pb.y; xc.z -= pb.z; xc.w -= pb.w;
  double ss = (double)xc.x * xc.x + (double)xc.y * xc.y
            + (double)xc.z * xc.z + (double)xc.w * xc.w;
  #pragma unroll
  for (int off = 32; off; off >>= 1) ss += __shfl_down(ss, off);
  __shared__ double wsum[3];
  if ((t & 63) == 0) wsum[t >> 6] = ss;
  __syncthreads();
  const double tot = wsum[0] + wsum[1] + wsum[2];
  const float nrm = (float)fmax(sqrt(tot), 1e-12);
  float4 o;
  o.x = xc.x / nrm; o.y = xc.y / nrm; o.z = xc.z / nrm; o.w = xc.w / nrm;
  *(float4*)&xn[(size_t)row * DIM + t * 4] = o;
  if (xnbf) {
    ushort4 h;
    h.x = f2bf(o.x); h.y = f2bf(o.y); h.z = f2bf(o.z); h.w = f2bf(o.w);
    *(ushort4*)&xnbf[(size_t)row * DIM + t * 4] = h;
  }
}

// ---------------------------------------------------------------------------
// Kernel 1b: enc_w fp32 -> bf16 (grid-stride float4 -> ushort4)
// ---------------------------------------------------------------------------
__global__ __launch_bounds__(256) void k_cvt(const float* __restrict__ W,
                                             unsigned short* __restrict__ Wbf) {
  const int n4 = LAT * DIM / 4;
  const int stride = gridDim.x * blockDim.x;
  for (int i = blockIdx.x * blockDim.x + threadIdx.x; i < n4; i += stride) {
    float4 v = *(const float4*)&W[(size_t)i * 4];
    ushort4 h;
    h.x = f2bf(v.x); h.y = f2bf(v.y); h.z = f2bf(v.z); h.w = f2bf(v.w);
    *(ushort4*)&Wbf[(size_t)i * 4] = h;
  }
}

// ---------------------------------------------------------------------------
// Kernel 2 (fast): bf16 MFMA screen GEMM. 128x128 tile, K-step 32, 4 waves,
// each wave a 64x64 quadrant (4x4 frags of 16x16x32). Double-buffered LDS,
// reg-staging. C/D layout per guide m89: col=lane&15, row=(lane>>4)*4+j.
// Screen values only — rescore recomputes in reference arithmetic.
// ---------------------------------------------------------------------------
__global__ __launch_bounds__(256) void k_gemm_bf16(const unsigned short* __restrict__ A,
                                                   const unsigned short* __restrict__ B,
                                                   const float* __restrict__ bias,
                                                   unsigned short* __restrict__ C) {
  __shared__ __align__(16) unsigned short Al[2][128 * 32];
  __shared__ __align__(16) unsigned short Bl[2][128 * 32];
  const int tid  = threadIdx.x;
  const int lane = tid & 63;
  const int wave = tid >> 6;
  const int bm = blockIdx.y * 128;
  const int bn = blockIdx.x * 128;
  const int wr = (wave >> 1) * 64;
  const int wc = (wave & 1) * 64;
  const int fr = lane & 15;
  const int fq = lane >> 4;
  const int r0 = tid >> 2;
  const int c0 = tid & 3;

  f32x4 acc[4][4];
  #pragma unroll
  for (int m = 0; m < 4; ++m)
    #pragma unroll
    for (int n = 0; n < 4; ++n) acc[m][n] = (f32x4){0.f, 0.f, 0.f, 0.f};

  uint4 ra0, ra1, rb0, rb1;
  ra0 = *(const uint4*)&A[(size_t)(bm + r0) * DIM + c0 * 8];
  ra1 = *(const uint4*)&A[(size_t)(bm + 64 + r0) * DIM + c0 * 8];
  rb0 = *(const uint4*)&B[(size_t)(bn + r0) * DIM + c0 * 8];
  rb1 = *(const uint4*)&B[(size_t)(bn + 64 + r0) * DIM + c0 * 8];
  *(uint4*)&Al[0][r0 * 32 + c0 * 8]        = ra0;
  *(uint4*)&Al[0][(64 + r0) * 32 + c0 * 8] = ra1;
  *(uint4*)&Bl[0][r0 * 32 + c0 * 8]        = rb0;
  *(uint4*)&Bl[0][(64 + r0) * 32 + c0 * 8] = rb1;

  const int NT = DIM / 32;   // 24
  for (int kt = 0; kt < NT; ++kt) {
    const int buf = kt & 1;
    __syncthreads();
    if (kt + 1 < NT) {
      const int k0 = (kt + 1) * 32;
      ra0 = *(const uint4*)&A[(size_t)(bm + r0) * DIM + k0 + c0 * 8];
      ra1 = *(const uint4*)&A[(size_t)(bm + 64 + r0) * DIM + k0 + c0 * 8];
      rb0 = *(const uint4*)&B[(size_t)(bn + r0) * DIM + k0 + c0 * 8];
      rb1 = *(const uint4*)&B[(size_t)(bn + 64 + r0) * DIM + k0 + c0 * 8];
    }
    bf16x8 af[4], bfr[4];
    #pragma unroll
    for (int m = 0; m < 4; ++m)
      af[m] = *(const bf16x8*)&Al[buf][(wr + m * 16 + fr) * 32 + fq * 8];
    #pragma unroll
    for (int n = 0; n < 4; ++n)
      bfr[n] = *(const bf16x8*)&Bl[buf][(wc + n * 16 + fr) * 32 + fq * 8];
    #pragma unroll
    for (int m = 0; m < 4; ++m)
      #pragma unroll
      for (int n = 0; n < 4; ++n)
        acc[m][n] = __builtin_amdgcn_mfma_f32_16x16x32_bf16(af[m], bfr[n], acc[m][n], 0, 0, 0);
    if (kt + 1 < NT) {
      const int wb = buf ^ 1;
      *(uint4*)&Al[wb][r0 * 32 + c0 * 8]        = ra0;
      *(uint4*)&Al[wb][(64 + r0) * 32 + c0 * 8] = ra1;
      *(uint4*)&Bl[wb][r0 * 32 + c0 * 8]        = rb0;
      *(uint4*)&Bl[wb][(64 + r0) * 32 + c0 * 8] = rb1;
    }
  }

  #pragma unroll
  for (int n = 0; n < 4; ++n) {
    const int col = bn + wc + n * 16 + fr;
    const float bv = bias[col];
    #pragma unroll
    for (int m = 0; m < 4; ++m) {
      #pragma unroll
      for (int j = 0; j < 4; ++j) {
        const int row = bm + wr + m * 16 + fq * 4 + j;
        C[(size_t)row * LAT + col] = f2bf(acc[m][n][j] + bv);
      }
    }
  }
}

// ---------------------------------------------------------------------------
// Kernel 3 (fast): screen candidate collection. One block (512 thr)/row.
// Collect all screen values >= (lower bin edge of screen's 32nd) - MARGIN.
// MARGIN 8e-3 > 2x strict worst-case screen-vs-fp32 error (~3.3e-3). Sound.
// ---------------------------------------------------------------------------
#define NBINS 8192
#define MARGIN 8e-3f
#define CCAP 192

__global__ __launch_bounds__(512) void k_screen(const unsigned short* __restrict__ S,
                                                int* __restrict__ cand_idx,   // [N_ROWS][CCAP]
                                                int* __restrict__ cand_cnt) { // [N_ROWS]
  const int row = blockIdx.x;
  const int t   = threadIdx.x;
  const unsigned short* rp = S + (size_t)row * LAT;

  float v[48];
  #pragma unroll
  for (int i = 0; i < 12; ++i) {
    ushort4 h = *(const ushort4*)&rp[(i * 512 + t) * 4];
    v[i * 4 + 0] = bf2f(h.x); v[i * 4 + 1] = bf2f(h.y);
    v[i * 4 + 2] = bf2f(h.z); v[i * 4 + 3] = bf2f(h.w);
  }

  __shared__ unsigned int hist[NBINS];
  __shared__ unsigned int csum[512];
  __shared__ unsigned int sh_chunk, sh_rchunk, sh_thru;
  __shared__ int sh_nc;
  if (t == 0) sh_nc = 0;
  #pragma unroll
  for (int i = 0; i < NBINS / 512; ++i) hist[t + i * 512] = 0u;
  __syncthreads();

  #pragma unroll
  for (int i = 0; i < 48; ++i) atomicAdd(&hist[mapf(v[i]) >> 19], 1u);
  __syncthreads();

  unsigned int cs = 0;
  #pragma unroll
  for (int i = 0; i < 16; ++i) cs += hist[t * 16 + i];
  csum[t] = cs;
  __syncthreads();
  for (int off = 1; off < 512; off <<= 1) {
    unsigned int add = (t + off < 512) ? csum[t + off] : 0u;
    __syncthreads();
    csum[t] += add;
    __syncthreads();
  }
  {
    const unsigned int nxt = (t + 1 < 512) ? csum[t + 1] : 0u;
    if (csum[t] >= KSEL && nxt < KSEL) { sh_chunk = (unsigned)t; sh_rchunk = nxt; }
  }
  __syncthreads();
  if (t == 0) {
    const unsigned int c0 = sh_chunk * 16u;
    unsigned int cum = sh_rchunk;
    unsigned int bin = c0;
    for (int b = 15; b >= 0; --b) {
      const unsigned int h = hist[c0 + b];
      if (cum + h >= KSEL) { bin = c0 + b; break; }
      cum += h;
    }
    const unsigned int lo = bin << 19;                       // bin lower edge (mapped)
    const unsigned int orig = (lo & 0x80000000u) ? (lo & 0x7FFFFFFFu) : ~lo;
    const float L = __uint_as_float(orig);
    sh_thru = mapf(L - MARGIN);
  }
  __syncthreads();
  const unsigned int thru = sh_thru;

  #pragma unroll
  for (int i = 0; i < 48; ++i) {
    if (mapf(v[i]) >= thru) {
      int p = atomicAdd(&sh_nc, 1);
      if (p < CCAP) cand_idx[row * CCAP + p] = ((i >> 2) * 512 + t) * 4 + (i & 3);
    }
  }
  __syncthreads();
  if (t == 0) cand_cnt[row] = (sh_nc < CCAP) ? sh_nc : CCAP;
}

// ---------------------------------------------------------------------------
// Kernel 4 (fast): REFERENCE-ORDER rescore. r5 lesson: exact fp64 still flips
// vs the reference => the ref embeds fp32 sgemm noise (min rank-gap over 8192
// rows ~4e-8 < fp32 noise 2e-7). BLAS sgemm accumulates each output with a
// SINGLE accumulator, sequential k ascending, FMA. Replicate exactly: one
// thread per candidate, acc = fmaf(xn[k], w[k], acc) for k=0..767, + bias.
// Then exact top-32 with reference tie semantics (keep v >= 32nd value).
// ---------------------------------------------------------------------------
__global__ __launch_bounds__(256) void k_rescore_seq(const float* __restrict__ xn,
                                                     const float* __restrict__ W,
                                                     const float* __restrict__ bias,
                                                     const int* __restrict__ cand_idx,
                                                     const int* __restrict__ cand_cnt,
                                                     float* __restrict__ tk_val,
                                                     int* __restrict__ tk_idx,
                                                     int* __restrict__ tk_cnt) {
  const int row = blockIdx.x;
  const int t   = threadIdx.x;
  const int cnt = cand_cnt[row];

  __shared__ float xs[DIM];
  __shared__ float rv[CCAP];
  __shared__ unsigned int sh_t;
  __shared__ int sh_kc;
  if (t == 0) sh_kc = 0;
  if (t < 192) *(float4*)&xs[t * 4] = *(const float4*)&xn[(size_t)row * DIM + t * 4];
  __syncthreads();

  if (t < cnt) {
    const int idx = cand_idx[row * CCAP + t];
    const float* wp = &W[(size_t)idx * DIM];
    float acc = 0.0f;
    for (int k4 = 0; k4 < DIM / 4; ++k4) {     // strictly sequential k, FMA
      const float4 wv = *(const float4*)&wp[k4 * 4];
      acc = fmaf(xs[k4 * 4 + 0], wv.x, acc);
      acc = fmaf(xs[k4 * 4 + 1], wv.y, acc);
      acc = fmaf(xs[k4 * 4 + 2], wv.z, acc);
      acc = fmaf(xs[k4 * 4 + 3], wv.w, acc);
    }
    rv[t] = acc + bias[idx];
  }
  __syncthreads();

  if (t < cnt) {
    const unsigned int uj = mapf(rv[t]);
    unsigned int g = 0, ge = 0;
    for (int i = 0; i < cnt; ++i) {
      const unsigned int ui = mapf(rv[i]);
      g  += (ui >  uj);
      ge += (ui >= uj);
    }
    if (g < KSEL && ge >= KSEL) sh_t = uj;   // 32nd largest value class
  }
  __syncthreads();
  if (t < cnt) {
    const float val = rv[t];
    if (mapf(val) >= sh_t) {
      int p = atomicAdd(&sh_kc, 1);
      if (p < 64) { tk_val[row * 64 + p] = val; tk_idx[row * 64 + p] = cand_idx[row * CCAP + t]; }
    }
  }
  __syncthreads();
  if (t == 0) tk_cnt[row] = (sh_kc < 64) ? sh_kc : 64;
}

// ---------------------------------------------------------------------------
// Kernel 5 (fast): zero-fill sparse row + scatter exact top-k values.
// ---------------------------------------------------------------------------
__global__ __launch_bounds__(256) void k_scatter(const float* __restrict__ tk_val,
                                                 const int* __restrict__ tk_idx,
                                                 const int* __restrict__ tk_cnt,
                                                 float* __restrict__ sparse) {
  const int row = blockIdx.x;
  const int t   = threadIdx.x;
  float* rp = sparse + (size_t)row * LAT;
  const float4 z = {0.f, 0.f, 0.f, 0.f};
  #pragma unroll
  for (int i = 0; i < LAT / (256 * 4); ++i) *(float4*)&rp[(i * 256 + t) * 4] = z;
  __syncthreads();
  if (t < tk_cnt[row]) rp[tk_idx[row * 64 + t]] = tk_val[row * 64 + t];
}

// ---------------------------------------------------------------------------
// Kernel 6: decode out[row] = sum_e val_e * enc_w[idx_e] + pre_bias
// (list-order accumulation noise ~3e-8 << 4.7e-3 threshold — no selection here)
// ---------------------------------------------------------------------------
__global__ __launch_bounds__(192) void k_dec(const float* __restrict__ tk_val,
                                             const int* __restrict__ tk_idx,
                                             const int* __restrict__ tk_cnt,
                                             const float* __restrict__ W,
                                             const float* __restrict__ pre_bias,
                                             float* __restrict__ out) {
  const int row = blockIdx.x;
  const int t   = threadIdx.x;
  const int cnt = tk_cnt[row];
  float4 acc = *(const float4*)&pre_bias[t * 4];
  for (int e = 0; e < cnt; ++e) {
    const float val = tk_val[row * 64 + e];
    const int   idx = tk_idx[row * 64 + e];
    const float4 w = *(const float4*)&W[(size_t)idx * DIM + t * 4];
    acc.x = fmaf(val, w.x, acc.x);
    acc.y = fmaf(val, w.y, acc.y);
    acc.z = fmaf(val, w.z, acc.z);
    acc.w = fmaf(val, w.w, acc.w);
  }
  *(float4*)&out[(size_t)row * DIM + t * 4] = acc;
}

// ===========================================================================
// Fallback fp32 path (ws too small). Note: k_gemm is also sequential-k FMA,
// so this path is hypothesis-consistent too.
// ===========================================================================
#define BM 128
#define BN 128
#define BK 32
#define PAD 4

__global__ __launch_bounds__(256) void k_gemm(const float* __restrict__ A,
                                              const float* __restrict__ B,
                                              const float* __restrict__ bias,
                                              float* __restrict__ C) {
  __shared__ float As[BK][BM + PAD];
  __shared__ float Bs[BK][BN + PAD];
  const int tid = threadIdx.x;
  const int bm = blockIdx.y * BM;
  const int bn = blockIdx.x * BN;
  const int tx = tid & 15;
  const int ty = tid >> 4;
  const int kq = tid & 7;
  const int rr = tid >> 3;

  float acc[8][8];
  #pragma unroll
  for (int i = 0; i < 8; ++i)
    #pragma unroll
    for (int j = 0; j < 8; ++j) acc[i][j] = 0.0f;

  float4 va[4], vb[4];
  #pragma unroll
  for (int i = 0; i < 4; ++i) {
    const int row = rr + 32 * i;
    va[i] = *(const float4*)&A[(size_t)(bm + row) * DIM + kq * 4];
    vb[i] = *(const float4*)&B[(size_t)(bn + row) * DIM + kq * 4];
  }

  for (int k0 = 0; k0 < DIM; k0 += BK) {
    #pragma unroll
    for (int i = 0; i < 4; ++i) {
      const int row = rr + 32 * i;
      As[kq * 4 + 0][row] = va[i].x; As[kq * 4 + 1][row] = va[i].y;
      As[kq * 4 + 2][row] = va[i].z; As[kq * 4 + 3][row] = va[i].w;
      Bs[kq * 4 + 0][row] = vb[i].x; Bs[kq * 4 + 1][row] = vb[i].y;
      Bs[kq * 4 + 2][row] = vb[i].z; Bs[kq * 4 + 3][row] = vb[i].w;
    }
    __syncthreads();
    if (k0 + BK < DIM) {
      #pragma unroll
      for (int i = 0; i < 4; ++i) {
        const int row = rr + 32 * i;
        va[i] = *(const float4*)&A[(size_t)(bm + row) * DIM + (k0 + BK) + kq * 4];
        vb[i] = *(const float4*)&B[(size_t)(bn + row) * DIM + (k0 + BK) + kq * 4];
      }
    }
    #pragma unroll
    for (int k = 0; k < BK; ++k) {
      float a[8], b[8];
      *(float4*)&b[0] = *(const float4*)&Bs[k][tx * 4];
      *(float4*)&b[4] = *(const float4*)&Bs[k][64 + tx * 4];
      *(float4*)&a[0] = *(const float4*)&As[k][ty * 8];
      *(float4*)&a[4] = *(const float4*)&As[k][ty * 8 + 4];
      #pragma unroll
      for (int i = 0; i < 8; ++i)
        #pragma unroll
        for (int j = 0; j < 8; ++j)
          acc[i][j] = fmaf(a[i], b[j], acc[i][j]);
    }
    __syncthreads();
  }

  const float4 b0 = *(const float4*)&bias[bn + tx * 4];
  const float4 b1 = *(const float4*)&bias[bn + 64 + tx * 4];
  #pragma unroll
  for (int i = 0; i < 8; ++i) {
    const size_t m = (size_t)(bm + ty * 8 + i);
    float4 v0, v1;
    v0.x = acc[i][0] + b0.x; v0.y = acc[i][1] + b0.y;
    v0.z = acc[i][2] + b0.z; v0.w = acc[i][3] + b0.w;
    v1.x = acc[i][4] + b1.x; v1.y = acc[i][5] + b1.y;
    v1.z = acc[i][6] + b1.z; v1.w = acc[i][7] + b1.w;
    *(float4*)&C[m * LAT + bn + tx * 4]      = v0;
    *(float4*)&C[m * LAT + bn + 64 + tx * 4] = v1;
  }
}

#define TPB_TK 512
#define CAND_CAP 512

template <int EMIT>
__global__ __launch_bounds__(TPB_TK) void k_topk(float* __restrict__ lat,
                                                 float* __restrict__ tk_val,
                                                 int* __restrict__ tk_idx,
                                                 int* __restrict__ tk_cnt) {
  const int row = blockIdx.x;
  const int t   = threadIdx.x;
  float* rowp = lat + (size_t)row * LAT;

  float4 v[12];
  #pragma unroll
  for (int i = 0; i < 12; ++i) v[i] = *(const float4*)&rowp[(i * TPB_TK + t) * 4];

  __shared__ unsigned int hist[NBINS];
  __shared__ unsigned int csum[TPB_TK];
  __shared__ unsigned int cand[CAND_CAP];
  __shared__ int sh_nc, sh_kc;
  __shared__ unsigned int sh_bin, sh_need, sh_thresh, sh_rchunk, sh_chunk;

  if (t == 0) { sh_nc = 0; sh_kc = 0; }
  #pragma unroll
  for (int i = 0; i < NBINS / TPB_TK; ++i) hist[t + i * TPB_TK] = 0u;
  __syncthreads();

  #pragma unroll
  for (int i = 0; i < 12; ++i) {
    atomicAdd(&hist[mapf(v[i].x) >> 19], 1u);
    atomicAdd(&hist[mapf(v[i].y) >> 19], 1u);
    atomicAdd(&hist[mapf(v[i].z) >> 19], 1u);
    atomicAdd(&hist[mapf(v[i].w) >> 19], 1u);
  }
  __syncthreads();

  unsigned int cs = 0;
  #pragma unroll
  for (int i = 0; i < 16; ++i) cs += hist[t * 16 + i];
  csum[t] = cs;
  __syncthreads();
  for (int off = 1; off < TPB_TK; off <<= 1) {
    unsigned int add = (t + off < TPB_TK) ? csum[t + off] : 0u;
    __syncthreads();
    csum[t] += add;
    __syncthreads();
  }
  {
    const unsigned int nxt = (t + 1 < TPB_TK) ? csum[t + 1] : 0u;
    if (csum[t] >= KSEL && nxt < KSEL) { sh_chunk = (unsigned)t; sh_rchunk = nxt; }
  }
  __syncthreads();
  if (t == 0) {
    const unsigned int c0 = sh_chunk * 16u;
    unsigned int cum = sh_rchunk;
    for (int b = 15; b >= 0; --b) {
      const unsigned int h = hist[c0 + b];
      if (cum + h >= KSEL) { sh_bin = c0 + b; sh_need = KSEL - cum; break; }
      cum += h;
    }
  }
  __syncthreads();
  const unsigned int bstar = sh_bin;

  #pragma unroll
  for (int i = 0; i < 12; ++i) {
    unsigned int u;
    u = mapf(v[i].x); if ((u >> 19) == bstar) { int p = atomicAdd(&sh_nc, 1); if (p < CAND_CAP) cand[p] = u; }
    u = mapf(v[i].y); if ((u >> 19) == bstar) { int p = atomicAdd(&sh_nc, 1); if (p < CAND_CAP) cand[p] = u; }
    u = mapf(v[i].z); if ((u >> 19) == bstar) { int p = atomicAdd(&sh_nc, 1); if (p < CAND_CAP) cand[p] = u; }
    u = mapf(v[i].w); if ((u >> 19) == bstar) { int p = atomicAdd(&sh_nc, 1); if (p < CAND_CAP) cand[p] = u; }
  }
  __syncthreads();
  const int nc = (sh_nc < CAND_CAP) ? sh_nc : CAND_CAP;
  const unsigned int need = sh_need;
  for (int j = t; j < nc; j += TPB_TK) {
    const unsigned int uj = cand[j];
    unsigned int g = 0, ge = 0;
    for (int i = 0; i < nc; ++i) {
      g  += (cand[i] >  uj);
      ge += (cand[i] >= uj);
    }
    if (g < need && ge >= need) sh_thresh = uj;
  }
  __syncthreads();
  const unsigned int tu = sh_thresh;

  #pragma unroll
  for (int i = 0; i < 12; ++i) {
    const int base = (i * TPB_TK + t) * 4;
    float4 o = v[i];
    unsigned int u;
    u = mapf(o.x); if (u >= tu) { if (EMIT) { int p = atomicAdd(&sh_kc, 1); if (p < 64) { tk_val[row * 64 + p] = o.x; tk_idx[row * 64 + p] = base + 0; } } } else o.x = 0.0f;
    u = mapf(o.y); if (u >= tu) { if (EMIT) { int p = atomicAdd(&sh_kc, 1); if (p < 64) { tk_val[row * 64 + p] = o.y; tk_idx[row * 64 + p] = base + 1; } } } else o.y = 0.0f;
    u = mapf(o.z); if (u >= tu) { if (EMIT) { int p = atomicAdd(&sh_kc, 1); if (p < 64) { tk_val[row * 64 + p] = o.z; tk_idx[row * 64 + p] = base + 2; } } } else o.z = 0.0f;
    u = mapf(o.w); if (u >= tu) { if (EMIT) { int p = atomicAdd(&sh_kc, 1); if (p < 64) { tk_val[row * 64 + p] = o.w; tk_idx[row * 64 + p] = base + 3; } } } else o.w = 0.0f;
    *(float4*)&rowp[base] = o;
  }
  if (EMIT) {
    __syncthreads();
    if (t == 0) tk_cnt[row] = (sh_kc < 64) ? sh_kc : 64;
  }
}

__global__ __launch_bounds__(256) void k_dec_scan(const float* __restrict__ sparse,
                                                  const float* __restrict__ W,
                                                  const float* __restrict__ pre_bias,
                                                  float* __restrict__ out) {
  const int row = blockIdx.x;
  const int t   = threadIdx.x;
  const float* rowp = sparse + (size_t)row * LAT;

  __shared__ float sval[96];
  __shared__ int   sidx[96];
  __shared__ int   scnt;
  if (t == 0) scnt = 0;
  __syncthreads();

  #pragma unroll
  for (int i = 0; i < LAT / (256 * 4); ++i) {
    const int base = (i * 256 + t) * 4;
    const float4 v = *(const float4*)&rowp[base];
    if (v.x != 0.0f) { int p = atomicAdd(&scnt, 1); if (p < 96) { sval[p] = v.x; sidx[p] = base + 0; } }
    if (v.y != 0.0f) { int p = atomicAdd(&scnt, 1); if (p < 96) { sval[p] = v.y; sidx[p] = base + 1; } }
    if (v.z != 0.0f) { int p = atomicAdd(&scnt, 1); if (p < 96) { sval[p] = v.z; sidx[p] = base + 2; } }
    if (v.w != 0.0f) { int p = atomicAdd(&scnt, 1); if (p < 96) { sval[p] = v.w; sidx[p] = base + 3; } }
  }
  __syncthreads();
  const int cnt = (scnt < 96) ? scnt : 96;

  if (t < 192) {
    float4 acc = *(const float4*)&pre_bias[t * 4];
    for (int e = 0; e < cnt; ++e) {
      const float val = sval[e];
      const float4 w = *(const float4*)&W[(size_t)sidx[e] * DIM + t * 4];
      acc.x = fmaf(val, w.x, acc.x);
      acc.y = fmaf(val, w.y, acc.y);
      acc.z = fmaf(val, w.z, acc.z);
      acc.w = fmaf(val, w.w, acc.w);
    }
    *(float4*)&out[(size_t)row * DIM + t * 4] = acc;
  }
}

// ---------------------------------------------------------------------------
extern "C" void kernel_launch(void* const* d_in, const int* in_sizes, int n_in,
                              void* d_out, int out_size, void* d_ws, size_t ws_size,
                              hipStream_t stream) {
  const float* x        = (const float*)d_in[0];
  const float* enc_w    = (const float*)d_in[1];
  const float* enc_b    = (const float*)d_in[2];
  const float* pre_bias = (const float*)d_in[3];

  float* out    = (float*)d_out;                          // [N_ROWS][DIM]
  float* sparse = (float*)d_out + (size_t)N_ROWS * DIM;   // [N_ROWS][LAT]
  float* xn     = out;  // xn staged in `out` region; decode overwrites last

  // bf16 staging inside the sparse output region (free until k_scatter):
  char* spb = (char*)sparse;
  unsigned short* xnbf   = (unsigned short*)spb;
  unsigned short* wbf    = (unsigned short*)(spb + (size_t)N_ROWS * DIM * 2);
  unsigned short* screen = (unsigned short*)(sparse + (size_t)N_ROWS * LAT / 2);

  // d_ws: small lists (~10.6 MB)
  char* wsb = (char*)d_ws;
  size_t off = 0;
  int*   cand_idx = (int*)(wsb + off); off += (size_t)N_ROWS * CCAP * 4;
  int*   cand_cnt = (int*)(wsb + off); off += (size_t)N_ROWS * 4;
  float* tk_val   = (float*)(wsb + off); off += (size_t)N_ROWS * 64 * 4;
  int*   tk_idx   = (int*)(wsb + off); off += (size_t)N_ROWS * 64 * 4;
  int*   tk_cnt   = (int*)(wsb + off); off += (size_t)N_ROWS * 4;
  const bool fast = ws_size >= off;

  if (fast) {
    k_norm<<<N_ROWS, 192, 0, stream>>>(x, pre_bias, xn, xnbf);
    k_cvt<<<2048, 256, 0, stream>>>(enc_w, wbf);
    dim3 ggrid(LAT / 128, N_ROWS / 128);
    k_gemm_bf16<<<ggrid, 256, 0, stream>>>(xnbf, wbf, enc_b, screen);
    k_screen<<<N_ROWS, 512, 0, stream>>>(screen, cand_idx, cand_cnt);
    k_rescore_seq<<<N_ROWS, 256, 0, stream>>>(xn, enc_w, enc_b, cand_idx, cand_cnt,
                                              tk_val, tk_idx, tk_cnt);
    k_scatter<<<N_ROWS, 256, 0, stream>>>(tk_val, tk_idx, tk_cnt, sparse);
    k_dec<<<N_ROWS, 192, 0, stream>>>(tk_val, tk_idx, tk_cnt, enc_w, pre_bias, out);
  } else {
    const size_t ws_small = (size_t)N_ROWS * 64 * 4 * 2 + (size_t)N_ROWS * 4;
    const bool use_lists = ws_size >= ws_small;
    float* f_val = (float*)d_ws;
    int*   f_idx = (int*)(f_val + (size_t)N_ROWS * 64);
    int*   f_cnt = f_idx + (size_t)N_ROWS * 64;

    k_norm<<<N_ROWS, 192, 0, stream>>>(x, pre_bias, xn, nullptr);
    dim3 ggrid(LAT / BN, N_ROWS / BM);
    k_gemm<<<ggrid, 256, 0, stream>>>(xn, enc_w, enc_b, sparse);
    if (use_lists) {
      k_topk<1><<<N_ROWS, TPB_TK, 0, stream>>>(sparse, f_val, f_idx, f_cnt);
      k_dec<<<N_ROWS, 192, 0, stream>>>(f_val, f_idx, f_cnt, enc_w, pre_bias, out);
    } else {
      k_topk<0><<<N_ROWS, TPB_TK, 0, stream>>>(sparse, nullptr, nullptr, nullptr);
      k_dec_scan<<<N_ROWS, 256, 0, stream>>>(sparse, enc_w, pre_bias, out);
    }
  }
}